// Round 1
// baseline (111.426 us; speedup 1.0000x reference)
//
#include <hip/hip_runtime.h>
#include <utility>

// ConvQuad2D as ONE pure GEMM over packed-f16 pair-features.
// r12 post-mortem: main kernel (~37us) runs at ~the un-overlapped sum of
// pipes: MFMA 12 + VALU 9 + DS 15.  DS is the largest pipe.
// r13: vertical tap reuse cut patch DS 100->60 b32/wave (neutral at harness).
// r14: column-window geometry — wave = 4 adjacent rows x 16 cols (tile
// 16x32), x staged TRANSPOSED in LDS ([c][ww][hh], XH=36) so each lane's
// tap window is 5 columns x 8 consecutive floats, all 16B-aligned:
// 10 ds_read_b128 replace 60 ds_read_b32 (DS/wave-tile 936->708 cy).
// Patch elements relabeled i' = kw*5 + kh (pairs run along the column
// axis); prep_frags translates with tr(i)=(i%5)*5+i/5 at weight fetch.
// Keeps r12: persistent 512 blocks, B staged once to LDS, x-halo register
// prefetch for tile t+1.
// Feature order (prep owns matching weights): slot s in [0,196):
//   s<181: pair (i,g), g in [i>>1,12]: (p_i*p_{2g}, p_i*p_{2g+1});
//          weights: j==i -> Wq[d,i,i]; j>i -> Wq[d,i,j]+Wq[d,j,i]; else 0
//   s<194: linear t=s-181: (p_{2t},p_{2t+1}) w/ Klin[j,d,o] (j==25 -> 0); else pad.
// k-slot: chunk c=s>>2, lane q = channel d, e = feature-in-chunk.

typedef _Float16 half2 __attribute__((ext_vector_type(2)));
typedef _Float16 half4 __attribute__((ext_vector_type(4)));
typedef _Float16 half8 __attribute__((ext_vector_type(8)));
typedef float floatx4 __attribute__((ext_vector_type(4)));

#define BB 8
#define HH 250
#define WW 250
#define NF 16
#define NSLOT_PAIR 181
#define NSLOT_LIN  13
#define NCHUNK     49              // 49*4 = 196 half2 slots = 392 features/channel
#define NFRAG      (NCHUNK * 64)   // 3136 B-fragments = 50,176 B

#define TW 16                 // tile width  (pixels)
#define TH 32                 // tile height = 8 waves x 4 rows
#define XW (TW + 4)           // 20 staged cols
#define XH (TH + 4)           // 36 staged rows
#define XSZ (XW * XH)         // 720 positions

#define NBLK     512          // persistent blocks (2/CU)
#define NTILE_W  16           // ceil(250/16)
#define NTILE_H  8            // ceil(250/32)
#define NTILES   (BB * NTILE_H * NTILE_W)   // 1024
#define NT       (NTILES / NBLK)            // 2 tiles per block

__host__ __device__ constexpr int slot_i(int s) {
    int i = 0, base = 0;
    while (base + (13 - (i >> 1)) <= s) { base += 13 - (i >> 1); ++i; }
    return i;
}
__host__ __device__ constexpr int slot_g(int s) {
    int i = 0, base = 0;
    while (base + (13 - (i >> 1)) <= s) { base += 13 - (i >> 1); ++i; }
    return (i >> 1) + (s - base);
}
// new-label (i' = kw*5+kh) -> reference-label (i = kh*5+kw); involution
__host__ __device__ constexpr int tr(int i) { return (i % 5) * 5 + (i / 5); }

// ---------- pre-pass: B fragments in MFMA lane order ----------
__global__ void prep_frags(const float* __restrict__ lin_w,   // (5,5,4,16)
                           const float* __restrict__ quad_w,  // (4,25,25,16)
                           _Float16* __restrict__ fragB) {
    const int c = blockIdx.x;       // 0..48
    const int lane = threadIdx.x;   // 0..63
    const int n = lane & 15;
    const int d = lane >> 4;
    half8 frag;
    #pragma unroll
    for (int e = 0; e < 8; ++e) {
        const int f = c * 8 + e;
        const int s = f >> 1, hf = f & 1;
        float v = 0.f;
        if (s < NSLOT_PAIR) {
            int i = 0, base = 0;
            while (base + (13 - (i >> 1)) <= s) { base += 13 - (i >> 1); ++i; }
            const int g = (i >> 1) + (s - base);
            const int j = 2 * g + hf;
            if (j == i)
                v = quad_w[((d * 25 + tr(i)) * 25 + tr(i)) * 16 + n];
            else if (j > i && j < 25)
                v = quad_w[((d * 25 + tr(i)) * 25 + tr(j)) * 16 + n]
                  + quad_w[((d * 25 + tr(j)) * 25 + tr(i)) * 16 + n];
        } else if (s < NSLOT_PAIR + NSLOT_LIN) {
            const int j = 2 * (s - NSLOT_PAIR) + hf;
            if (j < 25) v = lin_w[(tr(j) * 4 + d) * 16 + n];
        }
        frag[e] = (_Float16)v;
    }
    *(half8*)(fragB + (c * 64 + lane) * 8) = frag;
}

// ---------- packed helpers ----------
__device__ __forceinline__ half2 pk(float lo, float hi) {
    return __builtin_bit_cast(half2, __builtin_amdgcn_cvt_pkrtz(lo, hi));
}

template<int S>
__device__ __forceinline__ half2 slotval(const half2 (&pd2)[13]) {
    if constexpr (S < NSLOT_PAIR) {
        constexpr int i = slot_i(S), g = slot_g(S);
        constexpr int ir = i >> 1, ih = i & 1;
        const half2 src = pd2[ir];
        const half2 bi = {src[ih], src[ih]};   // op_sel broadcast
        return bi * pd2[g];                    // v_pk_mul_f16
    } else if constexpr (S < NSLOT_PAIR + NSLOT_LIN) {
        return pd2[S - NSLOT_PAIR];
    } else {
        return half2{(_Float16)0.f, (_Float16)0.f};
    }
}

template<int C>
__device__ __forceinline__ half8 make_frag(const half2 (&pd2)[13]) {
    const half2 a0 = slotval<C * 4 + 0>(pd2);
    const half2 a1 = slotval<C * 4 + 1>(pd2);
    const half2 a2 = slotval<C * 4 + 2>(pd2);
    const half2 a3 = slotval<C * 4 + 3>(pd2);
    const half4 lo = __builtin_shufflevector(a0, a1, 0, 1, 2, 3);
    const half4 hi = __builtin_shufflevector(a2, a3, 0, 1, 2, 3);
    return __builtin_shufflevector(lo, hi, 0, 1, 2, 3, 4, 5, 6, 7);
}

template<size_t... Cs>
__device__ __forceinline__ void gemm_all(
    const half2 (&p0)[13], const half2 (&p1)[13],
    const half2 (&p2)[13], const half2 (&p3)[13],
    const _Float16* sBlane,
    floatx4& a0, floatx4& a1, floatx4& a2, floatx4& a3,
    std::index_sequence<Cs...>) {
    (([&] {
        constexpr int C = (int)Cs;
        const half8 bf = *(const half8*)(sBlane + C * 64 * 8);  // ds_read_b128 imm
        a0 = __builtin_amdgcn_mfma_f32_16x16x32_f16(make_frag<C>(p0), bf, a0, 0, 0, 0);
        a1 = __builtin_amdgcn_mfma_f32_16x16x32_f16(make_frag<C>(p1), bf, a1, 0, 0, 0);
        a2 = __builtin_amdgcn_mfma_f32_16x16x32_f16(make_frag<C>(p2), bf, a2, 0, 0, 0);
        a3 = __builtin_amdgcn_mfma_f32_16x16x32_f16(make_frag<C>(p3), bf, a3, 0, 0, 0);
    }()), ...);
}

// ---------- 5-column x 8-row window -> four row-patches ----------
// xt is TRANSPOSED: [c][ww][hh], column = XH consecutive floats.
// base = q*XSZ + m*XH + 4*wv  (16B-aligned for every lane).
// Patch label i' = kw*5 + kh; element i' at row rr = col[kw][i'%5 + rr].
// Streams columns (2 x ds_read_b128 each) with a 1-element carry per row
// for the two cross-column pairs (t=2: i'=4,5 and t=7: i'=14,15).
__device__ __forceinline__ void patches_cols(const float* xt, int base,
                                             half2 (&pd)[4][13]) {
    float carry[4];
    #pragma unroll
    for (int cc = 0; cc < 5; ++cc) {
        const float4 lo = *(const float4*)(xt + base + cc * XH);
        const float4 hi = *(const float4*)(xt + base + cc * XH + 4);
        float col[8];
        col[0] = lo.x; col[1] = lo.y; col[2] = lo.z; col[3] = lo.w;
        col[4] = hi.x; col[5] = hi.y; col[6] = hi.z; col[7] = hi.w;
        #pragma unroll
        for (int rr = 0; rr < 4; ++rr) {
            if (cc == 0) {
                pd[rr][0] = pk(col[0 + rr], col[1 + rr]);
                pd[rr][1] = pk(col[2 + rr], col[3 + rr]);
                carry[rr] = col[4 + rr];
            } else if (cc == 1) {
                pd[rr][2] = pk(carry[rr], col[0 + rr]);
                pd[rr][3] = pk(col[1 + rr], col[2 + rr]);
                pd[rr][4] = pk(col[3 + rr], col[4 + rr]);
            } else if (cc == 2) {
                pd[rr][5] = pk(col[0 + rr], col[1 + rr]);
                pd[rr][6] = pk(col[2 + rr], col[3 + rr]);
                carry[rr] = col[4 + rr];
            } else if (cc == 3) {
                pd[rr][7] = pk(carry[rr], col[0 + rr]);
                pd[rr][8] = pk(col[1 + rr], col[2 + rr]);
                pd[rr][9] = pk(col[3 + rr], col[4 + rr]);
            } else {
                pd[rr][10] = pk(col[0 + rr], col[1 + rr]);
                pd[rr][11] = pk(col[2 + rr], col[3 + rr]);
                pd[rr][12] = pk(col[4 + rr], 0.f);
            }
        }
    }
}

// ---------- tile index -> (b, h0, w0) ----------
__device__ __forceinline__ void tile_coords(int T, int& b, int& h0, int& w0) {
    b = T >> 7;                  // 128 tiles per batch image (16w x 8h)
    const int rem = T & 127;
    h0 = (rem >> 4) * TH;
    w0 = (rem & 15) * TW;
}

// ---------- x-halo prefetch into registers (2 positions/thread) ----------
__device__ __forceinline__ void xload_regs(const float* __restrict__ x,
                                           int b, int h0, int w0,
                                           float4& v0, float4& v1) {
    const int p0 = threadIdx.x;
    {
        const int hh = p0 / XW, ww = p0 % XW;
        const int r = h0 + hh - 2, c = w0 + ww - 2;
        v0 = make_float4(0.f, 0.f, 0.f, 0.f);
        if (p0 < XSZ && (unsigned)r < (unsigned)HH && (unsigned)c < (unsigned)WW)
            v0 = ((const float4*)x)[(b * HH + r) * WW + c];
    }
    const int p1 = p0 + 512;
    v1 = make_float4(0.f, 0.f, 0.f, 0.f);
    if (p1 < XSZ) {
        const int hh = p1 / XW, ww = p1 % XW;
        const int r = h0 + hh - 2, c = w0 + ww - 2;
        if ((unsigned)r < (unsigned)HH && (unsigned)c < (unsigned)WW)
            v1 = ((const float4*)x)[(b * HH + r) * WW + c];
    }
}

// transposed write: xt[c][ww][hh]
__device__ __forceinline__ void xwrite_lds(float* xt, const float4& v0, const float4& v1) {
    const int p0 = threadIdx.x;
    if (p0 < XSZ) {
        const int hh = p0 / XW, ww = p0 % XW;
        const int idx = ww * XH + hh;
        xt[0 * XSZ + idx] = v0.x;
        xt[1 * XSZ + idx] = v0.y;
        xt[2 * XSZ + idx] = v0.z;
        xt[3 * XSZ + idx] = v0.w;
    }
    const int p1 = p0 + 512;
    if (p1 < XSZ) {
        const int hh = p1 / XW, ww = p1 % XW;
        const int idx = ww * XH + hh;
        xt[0 * XSZ + idx] = v1.x;
        xt[1 * XSZ + idx] = v1.y;
        xt[2 * XSZ + idx] = v1.z;
        xt[3 * XSZ + idx] = v1.w;
    }
}

// ---------- main kernel: 512 persistent threads, 2 tiles per block ----------
// wave wv = 4 adjacent rows (h0+4wv..+3) x 16 cols; acc rr -> row rr.
__global__ __launch_bounds__(512, 4) void convquad_gemm(
    const float* __restrict__ x,       // (8,250,250,4)
    const float* __restrict__ bias,    // (16,)
    const _Float16* __restrict__ fragB,
    float* __restrict__ out)           // (8,250,250,16)
{
    __shared__ __align__(16) float xt[4 * XSZ];       // 11,520 B: [c][ww][hh]
    __shared__ __align__(16) _Float16 sB[NFRAG * 8];  // 50,176 B

    const int lane = threadIdx.x & 63;
    const int wv = threadIdx.x >> 6;     // row-quad within tile
    const int m = lane & 15;             // pixel col within 16-col tile; also o
    const int q = lane >> 4;             // channel for A; row-quad for D
    const float bo = bias[m];

    // ---- prologue: prefetch x (tile 0) + copy B, one barrier ----
    int b, h0, w0;
    tile_coords(blockIdx.x, b, h0, w0);
    float4 v0, v1;
    xload_regs(x, b, h0, w0, v0, v1);

    {   // coalesced 50KB B copy: global (L2-hot) -> LDS
        const float4* src = (const float4*)fragB;
        float4* dst = (float4*)sB;
        #pragma unroll
        for (int t = threadIdx.x; t < NFRAG * 8 / 8; t += 512) dst[t] = src[t];
    }
    xwrite_lds(xt, v0, v1);
    __syncthreads();

    #pragma unroll 1
    for (int t = 0; t < NT; ++t) {
        // prefetch next tile's x-halo into registers (latency hides under compute)
        int bn, h0n, w0n;
        if (t + 1 < NT) {
            tile_coords(blockIdx.x + (t + 1) * NBLK, bn, h0n, w0n);
            xload_regs(x, bn, h0n, w0n, v0, v1);
        }

        // ---- patches: 5x8 column window serves 4 row-patches ----
        const int base = q * XSZ + m * XH + 4 * wv;
        half2 pd[4][13];
        patches_cols(xt, base, pd);

        floatx4 acc0 = {bo, bo, bo, bo};
        floatx4 acc1 = acc0, acc2 = acc0, acc3 = acc0;
        gemm_all(pd[0], pd[1], pd[2], pd[3], sB + lane * 8,
                 acc0, acc1, acc2, acc3, std::make_index_sequence<NCHUNK>{});

        // ---- store: acc rr -> row r0+rr, pixel col w0 + q*4 + r, feature m ----
        const int r0 = h0 + 4 * wv;
        #pragma unroll
        for (int rr = 0; rr < 4; ++rr) {
            const int h = r0 + rr;
            if (h < HH) {
                const int rowbase = (b * HH + h) * WW;
                const floatx4& a = (rr == 0) ? acc0 : (rr == 1) ? acc1
                                 : (rr == 2) ? acc2 : acc3;
                #pragma unroll
                for (int r = 0; r < 4; ++r) {
                    const int w = w0 + q * 4 + r;
                    if (w < WW) out[(rowbase + w) * NF + m] = a[r];
                }
            }
        }

        // ---- swap in next tile's x (cheap: regs->LDS + barriers) ----
        if (t + 1 < NT) {
            b = bn; h0 = h0n; w0 = w0n;
            __syncthreads();              // everyone done reading xt
            xwrite_lds(xt, v0, v1);
            __syncthreads();              // writes visible
        }
    }
}

extern "C" void kernel_launch(void* const* d_in, const int* in_sizes, int n_in,
                              void* d_out, int out_size, void* d_ws, size_t ws_size,
                              hipStream_t stream) {
    const float* x      = (const float*)d_in[0];
    const float* lin_w  = (const float*)d_in[1];
    const float* quad_w = (const float*)d_in[2];
    const float* bias   = (const float*)d_in[3];
    float* out = (float*)d_out;
    _Float16* fragB = (_Float16*)d_ws;   // 50,176 B

    prep_frags<<<dim3(NCHUNK), dim3(64), 0, stream>>>(lin_w, quad_w, fragB);

    convquad_gemm<<<dim3(NBLK), dim3(512), 0, stream>>>(x, bias, fragB, out);
}

// Round 2
// 100.057 us; speedup vs baseline: 1.1136x; 1.1136x over previous
//
#include <hip/hip_runtime.h>
#include <utility>

// ConvQuad2D as ONE pure GEMM over packed-f16 pair-features.
// r12 post-mortem: main kernel (~37us) ~ sum of pipes MFMA 12.7 + VALU 9 +
// DS 15 — but no pipe >40% busy => LATENCY-bound at fixed 4 waves/SIMD
// (LDS 61.7KB/block -> 2 blocks/CU; VGPR 128 cap -> 4 waves/SIMD).
// r13: vertical tap reuse (DS -40%) neutral -> confirms not DS-throughput.
// r14: column-window b128 geometry (DS -65%) REGRESSED ~6us (suspect VGPR
// pressure from pd[4][13] + 10 hoisted b128 loads) -> reverted.
// r15: back to r13 geometry + two latency attacks at fixed occupancy:
//   (1) explicit 2-deep rotating B-frag prefetch (bf0/bf1 named regs):
//       each chunk's ds_read_b128 issued ~2 chunk-periods before use;
//   (2) s_setprio(1) around each 4-MFMA cluster (T5; the 2 co-resident
//       blocks are barrier-independent -> role diversity exists).
// Keeps r12: persistent 512 blocks, B staged once to LDS, x-halo register
// prefetch for tile t+1; wave = 2 adjacent rows x 2 col-groups (tile 32x16),
// lane loads a 6x5 tap window (30 b32) per col-group serving BOTH rows.
// Feature order (prep owns matching weights): slot s in [0,196):
//   s<181: pair (i,g), g in [i>>1,12]: (p_i*p_{2g}, p_i*p_{2g+1});
//          weights: j==i -> Wq[d,i,i]; j>i -> Wq[d,i,j]+Wq[d,j,i]; else 0
//   s<194: linear t=s-181: (p_{2t},p_{2t+1}) w/ Klin[j,d,o] (j==25 -> 0); else pad.
// k-slot: chunk c=s>>2, lane q = channel d, e = feature-in-chunk.

typedef _Float16 half2 __attribute__((ext_vector_type(2)));
typedef _Float16 half4 __attribute__((ext_vector_type(4)));
typedef _Float16 half8 __attribute__((ext_vector_type(8)));
typedef float floatx4 __attribute__((ext_vector_type(4)));

#define BB 8
#define HH 250
#define WW 250
#define NF 16
#define NSLOT_PAIR 181
#define NSLOT_LIN  13
#define NCHUNK     49              // 49*4 = 196 half2 slots = 392 features/channel
#define NFRAG      (NCHUNK * 64)   // 3136 B-fragments = 50,176 B

#define TW 32                 // tile width  (pixels) = 2 col-groups of 16
#define TH 16                 // tile height = 8 waves x 2 rows
#define XW (TW + 4)           // 36 staged cols
#define XH (TH + 4)           // 20 staged rows
#define XSZ (XW * XH)         // 720 positions

#define NBLK     512          // persistent blocks (2/CU)
#define NTILE_W  8            // ceil(250/32)
#define NTILE_H  16           // ceil(250/16)
#define NTILES   (BB * NTILE_H * NTILE_W)   // 1024
#define NT       (NTILES / NBLK)            // 2 tiles per block

__host__ __device__ constexpr int slot_i(int s) {
    int i = 0, base = 0;
    while (base + (13 - (i >> 1)) <= s) { base += 13 - (i >> 1); ++i; }
    return i;
}
__host__ __device__ constexpr int slot_g(int s) {
    int i = 0, base = 0;
    while (base + (13 - (i >> 1)) <= s) { base += 13 - (i >> 1); ++i; }
    return (i >> 1) + (s - base);
}

// ---------- pre-pass: B fragments in MFMA lane order ----------
__global__ void prep_frags(const float* __restrict__ lin_w,   // (5,5,4,16)
                           const float* __restrict__ quad_w,  // (4,25,25,16)
                           _Float16* __restrict__ fragB) {
    const int c = blockIdx.x;       // 0..48
    const int lane = threadIdx.x;   // 0..63
    const int n = lane & 15;
    const int d = lane >> 4;
    half8 frag;
    #pragma unroll
    for (int e = 0; e < 8; ++e) {
        const int f = c * 8 + e;
        const int s = f >> 1, hf = f & 1;
        float v = 0.f;
        if (s < NSLOT_PAIR) {
            int i = 0, base = 0;
            while (base + (13 - (i >> 1)) <= s) { base += 13 - (i >> 1); ++i; }
            const int g = (i >> 1) + (s - base);
            const int j = 2 * g + hf;
            if (j == i)
                v = quad_w[((d * 25 + i) * 25 + i) * 16 + n];
            else if (j > i && j < 25)
                v = quad_w[((d * 25 + i) * 25 + j) * 16 + n]
                  + quad_w[((d * 25 + j) * 25 + i) * 16 + n];
        } else if (s < NSLOT_PAIR + NSLOT_LIN) {
            const int j = 2 * (s - NSLOT_PAIR) + hf;
            if (j < 25) v = lin_w[(j * 4 + d) * 16 + n];
        }
        frag[e] = (_Float16)v;
    }
    *(half8*)(fragB + (c * 64 + lane) * 8) = frag;
}

// ---------- packed helpers ----------
__device__ __forceinline__ half2 pk(float lo, float hi) {
    return __builtin_bit_cast(half2, __builtin_amdgcn_cvt_pkrtz(lo, hi));
}

template<int S>
__device__ __forceinline__ half2 slotval(const half2 (&pd2)[13]) {
    if constexpr (S < NSLOT_PAIR) {
        constexpr int i = slot_i(S), g = slot_g(S);
        constexpr int ir = i >> 1, ih = i & 1;
        const half2 src = pd2[ir];
        const half2 bi = {src[ih], src[ih]};   // op_sel broadcast
        return bi * pd2[g];                    // v_pk_mul_f16
    } else if constexpr (S < NSLOT_PAIR + NSLOT_LIN) {
        return pd2[S - NSLOT_PAIR];
    } else {
        return half2{(_Float16)0.f, (_Float16)0.f};
    }
}

template<int C>
__device__ __forceinline__ half8 make_frag(const half2 (&pd2)[13]) {
    const half2 a0 = slotval<C * 4 + 0>(pd2);
    const half2 a1 = slotval<C * 4 + 1>(pd2);
    const half2 a2 = slotval<C * 4 + 2>(pd2);
    const half2 a3 = slotval<C * 4 + 3>(pd2);
    const half4 lo = __builtin_shufflevector(a0, a1, 0, 1, 2, 3);
    const half4 hi = __builtin_shufflevector(a2, a3, 0, 1, 2, 3);
    return __builtin_shufflevector(lo, hi, 0, 1, 2, 3, 4, 5, 6, 7);
}

// r15: explicit 2-deep rotating B prefetch + setprio around MFMA cluster.
template<size_t... Cs>
__device__ __forceinline__ void gemm_all(
    const half2 (&p0)[13], const half2 (&p1)[13],
    const half2 (&p2)[13], const half2 (&p3)[13],
    const _Float16* sBlane,
    floatx4& a0, floatx4& a1, floatx4& a2, floatx4& a3,
    std::index_sequence<Cs...>) {
    const half8* B = (const half8*)sBlane;   // frag C at B[C*64] (imm offs C*1024B)
    half8 bf0 = B[0 * 64];
    half8 bf1 = B[1 * 64];
    (([&] {
        constexpr int C = (int)Cs;
        const half8 bf = bf0;                // frag for chunk C (issued at C-2)
        bf0 = bf1;
        if constexpr (C + 2 < NCHUNK) bf1 = B[(C + 2) * 64];
        __builtin_amdgcn_s_setprio(1);
        a0 = __builtin_amdgcn_mfma_f32_16x16x32_f16(make_frag<C>(p0), bf, a0, 0, 0, 0);
        a1 = __builtin_amdgcn_mfma_f32_16x16x32_f16(make_frag<C>(p1), bf, a1, 0, 0, 0);
        a2 = __builtin_amdgcn_mfma_f32_16x16x32_f16(make_frag<C>(p2), bf, a2, 0, 0, 0);
        a3 = __builtin_amdgcn_mfma_f32_16x16x32_f16(make_frag<C>(p3), bf, a3, 0, 0, 0);
        __builtin_amdgcn_s_setprio(0);
    }()), ...);
}

// ---------- 6x5 tap window -> two row-patches (vertical reuse) ----------
__device__ __forceinline__ void patches_from_window(const float* xt, int base,
                                                    half2 (&pdT)[13], half2 (&pdB)[13]) {
    float t6[6][5];
    #pragma unroll
    for (int rr = 0; rr < 6; ++rr)
        #pragma unroll
        for (int cc = 0; cc < 5; ++cc)
            t6[rr][cc] = xt[base + rr * XW + cc];

    float pf0[26], pf1[26];
    pf0[25] = 0.f; pf1[25] = 0.f;
    #pragma unroll
    for (int rr = 0; rr < 5; ++rr)
        #pragma unroll
        for (int cc = 0; cc < 5; ++cc) {
            pf0[rr * 5 + cc] = t6[rr][cc];       // pixel at row r0
            pf1[rr * 5 + cc] = t6[rr + 1][cc];   // pixel at row r0+1
        }
    #pragma unroll
    for (int t = 0; t < 13; ++t) {
        pdT[t] = pk(pf0[2 * t], pf0[2 * t + 1]);
        pdB[t] = pk(pf1[2 * t], pf1[2 * t + 1]);
    }
}

// ---------- tile index -> (b, h0, w0) ----------
__device__ __forceinline__ void tile_coords(int T, int& b, int& h0, int& w0) {
    b = T >> 7;                  // 128 tiles per batch image (8w x 16h)
    const int rem = T & 127;
    h0 = (rem >> 3) * TH;
    w0 = (rem & 7) * TW;
}

// ---------- x-halo prefetch into registers (2 positions/thread) ----------
__device__ __forceinline__ void xload_regs(const float* __restrict__ x,
                                           int b, int h0, int w0,
                                           float4& v0, float4& v1) {
    const int p0 = threadIdx.x;
    {
        const int hh = p0 / XW, ww = p0 % XW;
        const int r = h0 + hh - 2, c = w0 + ww - 2;
        v0 = make_float4(0.f, 0.f, 0.f, 0.f);
        if (p0 < XSZ && (unsigned)r < (unsigned)HH && (unsigned)c < (unsigned)WW)
            v0 = ((const float4*)x)[(b * HH + r) * WW + c];
    }
    const int p1 = p0 + 512;
    v1 = make_float4(0.f, 0.f, 0.f, 0.f);
    if (p1 < XSZ) {
        const int hh = p1 / XW, ww = p1 % XW;
        const int r = h0 + hh - 2, c = w0 + ww - 2;
        if ((unsigned)r < (unsigned)HH && (unsigned)c < (unsigned)WW)
            v1 = ((const float4*)x)[(b * HH + r) * WW + c];
    }
}

__device__ __forceinline__ void xwrite_lds(float* xt, const float4& v0, const float4& v1) {
    const int p0 = threadIdx.x;
    if (p0 < XSZ) {
        xt[0 * XSZ + p0] = v0.x;
        xt[1 * XSZ + p0] = v0.y;
        xt[2 * XSZ + p0] = v0.z;
        xt[3 * XSZ + p0] = v0.w;
    }
    const int p1 = p0 + 512;
    if (p1 < XSZ) {
        xt[0 * XSZ + p1] = v1.x;
        xt[1 * XSZ + p1] = v1.y;
        xt[2 * XSZ + p1] = v1.z;
        xt[3 * XSZ + p1] = v1.w;
    }
}

// ---------- main kernel: 512 persistent threads, 2 tiles per block ----------
// wave = 2 adjacent rows x 32 cols; segments: (r0,c0-15),(r0,c16-31),(r1,c0-15),(r1,c16-31)
__global__ __launch_bounds__(512, 4) void convquad_gemm(
    const float* __restrict__ x,       // (8,250,250,4)
    const float* __restrict__ bias,    // (16,)
    const _Float16* __restrict__ fragB,
    float* __restrict__ out)           // (8,250,250,16)
{
    __shared__ float xt[4 * XSZ];                     // 11,520 B: [c][hh][ww]
    __shared__ __align__(16) _Float16 sB[NFRAG * 8];  // 50,176 B

    const int lane = threadIdx.x & 63;
    const int wv = threadIdx.x >> 6;     // row-pair within tile
    const int m = lane & 15;             // pixel within 16-col segment; also o
    const int q = lane >> 4;             // channel for A; row-quad for D
    const float bo = bias[m];

    // ---- prologue: prefetch x (tile 0) + copy B, one barrier ----
    int b, h0, w0;
    tile_coords(blockIdx.x, b, h0, w0);
    float4 v0, v1;
    xload_regs(x, b, h0, w0, v0, v1);

    {   // coalesced 50KB B copy: global (L2-hot) -> LDS
        const float4* src = (const float4*)fragB;
        float4* dst = (float4*)sB;
        #pragma unroll
        for (int t = threadIdx.x; t < NFRAG * 8 / 8; t += 512) dst[t] = src[t];
    }
    xwrite_lds(xt, v0, v1);
    __syncthreads();

    #pragma unroll 1
    for (int t = 0; t < NT; ++t) {
        // prefetch next tile's x-halo into registers (latency hides under compute)
        int bn, h0n, w0n;
        if (t + 1 < NT) {
            tile_coords(blockIdx.x + (t + 1) * NBLK, bn, h0n, w0n);
            xload_regs(x, bn, h0n, w0n, v0, v1);
        }

        // ---- patches: 6x5 window per col-group serves both rows ----
        const int base = q * XSZ + (2 * wv) * XW + m;
        half2 pd0[13], pd1[13], pd2[13], pd3[13];
        patches_from_window(xt, base,      pd0, pd2);   // col-group 0: rows r0, r1
        patches_from_window(xt, base + 16, pd1, pd3);   // col-group 1: rows r0, r1

        floatx4 acc0 = {bo, bo, bo, bo};
        floatx4 acc1 = acc0, acc2 = acc0, acc3 = acc0;
        gemm_all(pd0, pd1, pd2, pd3, sB + lane * 8,
                 acc0, acc1, acc2, acc3, std::make_index_sequence<NCHUNK>{});

        // ---- store: seg0/1 -> row r0, seg2/3 -> row r1 ----
        const int r0 = h0 + 2 * wv;
        #pragma unroll
        for (int rr = 0; rr < 2; ++rr) {
            const int h = r0 + rr;
            if (h < HH) {
                const int rowbase = (b * HH + h) * WW;
                const floatx4& aA = rr ? acc2 : acc0;
                const floatx4& aB = rr ? acc3 : acc1;
                #pragma unroll
                for (int r = 0; r < 4; ++r) {
                    const int wA = w0 + q * 4 + r;
                    if (wA < WW) out[(rowbase + wA) * NF + m] = aA[r];
                    const int wB = w0 + 16 + q * 4 + r;
                    if (wB < WW) out[(rowbase + wB) * NF + m] = aB[r];
                }
            }
        }

        // ---- swap in next tile's x (cheap: regs->LDS + barriers) ----
        if (t + 1 < NT) {
            b = bn; h0 = h0n; w0 = w0n;
            __syncthreads();              // everyone done reading xt
            xwrite_lds(xt, v0, v1);
            __syncthreads();              // writes visible
        }
    }
}

extern "C" void kernel_launch(void* const* d_in, const int* in_sizes, int n_in,
                              void* d_out, int out_size, void* d_ws, size_t ws_size,
                              hipStream_t stream) {
    const float* x      = (const float*)d_in[0];
    const float* lin_w  = (const float*)d_in[1];
    const float* quad_w = (const float*)d_in[2];
    const float* bias   = (const float*)d_in[3];
    float* out = (float*)d_out;
    _Float16* fragB = (_Float16*)d_ws;   // 50,176 B

    prep_frags<<<dim3(NCHUNK), dim3(64), 0, stream>>>(lin_w, quad_w, fragB);

    convquad_gemm<<<dim3(NBLK), dim3(512), 0, stream>>>(x, bias, fragB, out);
}